// Round 7
// baseline (417.676 us; speedup 1.0000x reference)
//
#include <hip/hip_runtime.h>
#include <hip/hip_bf16.h>

#define N_NODES 10000
#define N_EDGES 160000
#define DD 1024
#define KCAT 2048
#define MPAD 10240
#define NKT 32                   // K-tiles = KCAT/64
#define GBLK 160                 // 40 m-tiles x 4 n-tiles, 256x256 each

// agg grid: 8 column-slices (one per XCD via blockIdx%8) x 250 blocks
#define AGG_BLOCKS 2000
#define AGG_WPS 1000

typedef __attribute__((ext_vector_type(8))) __bf16 bf16x8;
typedef __attribute__((ext_vector_type(4))) __bf16 bf16x4;
typedef __attribute__((ext_vector_type(4))) float f32x4;

__device__ inline void gload_lds16(const void* g, void* l) {
  __builtin_amdgcn_global_load_lds((const __attribute__((address_space(1))) void*)g,
                                   (__attribute__((address_space(3))) void*)l, 16, 0, 0);
}

// ---------------- prep1: hist (blocks 0..624) + embed gather (blocks 625..10624) ----
__global__ __launch_bounds__(256) void k_prep1(const int* __restrict__ dst,
                                               int* __restrict__ deg,
                                               const int* __restrict__ node,
                                               const float* __restrict__ emb,
                                               __bf16* __restrict__ xcat) {
  int b = blockIdx.x;
  if (b < 625) {
    int e = b * 256 + threadIdx.x;
    if (e < N_EDGES) atomicAdd(&deg[dst[e]], 1);
  } else {
    int i = b - 625;          // node 0..9999
    int t = threadIdx.x;
    float4 v = ((const float4*)(emb + (size_t)node[i] * DD))[t];
    bf16x4 o;
    o[0] = (__bf16)v.x; o[1] = (__bf16)v.y; o[2] = (__bf16)v.z; o[3] = (__bf16)v.w;
    *(bf16x4*)(xcat + (size_t)i * KCAT + t * 4) = o;
  }
}

// coalesced chunked scan: 10 chunks x 1024 contiguous, 2 barriers/chunk
__global__ __launch_bounds__(1024) void k_scan(const int* __restrict__ deg,
                                               int* __restrict__ off) {
  __shared__ int wtot[16];
  __shared__ int wpre[16];
  __shared__ int carry_s;
  int t = threadIdx.x, lane = t & 63, w = t >> 6;
  if (t == 0) carry_s = 0;
  __syncthreads();
  for (int c = 0; c < 10; ++c) {
    int idx = c * 1024 + t;
    int v = (idx < N_NODES) ? deg[idx] : 0;
    int inc = v;
#pragma unroll
    for (int d = 1; d < 64; d <<= 1) {
      int y = __shfl_up(inc, d);
      if (lane >= d) inc += y;
    }
    if (lane == 63) wtot[w] = inc;
    __syncthreads();
    if (t == 0) {
      int acc = carry_s;
      for (int k = 0; k < 16; ++k) { wpre[k] = acc; acc += wtot[k]; }
      carry_s = acc;
    }
    __syncthreads();
    if (idx < N_NODES) off[idx] = wpre[w] + (inc - v);
  }
  if (t == 0) off[N_NODES] = carry_s;
}

// ---------------- prep2: fill (blocks 0..624) + wconv (blocks 625..4720) ----------
__global__ __launch_bounds__(256) void k_prep2(const int* __restrict__ src,
                                               const int* __restrict__ dstv,
                                               const int* __restrict__ off,
                                               int* __restrict__ cursor,
                                               int* __restrict__ eidx,
                                               const float* __restrict__ W1s,
                                               const float* __restrict__ W1n,
                                               const float* __restrict__ W2s,
                                               const float* __restrict__ W2n,
                                               __bf16* __restrict__ Wt1,
                                               __bf16* __restrict__ Wt2) {
  int b = blockIdx.x;
  if (b < 625) {
    int e = b * 256 + threadIdx.x;
    if (e < N_EDGES) {
      int d = dstv[e];
      int pos = atomicAdd(&cursor[d], 1);
      eidx[off[d] + pos] = src[e];
    }
    return;
  }
  int id = b - 625;            // 0..4095
  int k0 = (id & 63) * 32;     // 0..2047
  int c0 = ((id >> 6) & 31) * 32;
  int lay = id >> 11;
  const float* Ws = lay ? W2s : W1s;
  const float* Wn = lay ? W2n : W1n;
  __bf16* Wt = lay ? Wt2 : Wt1;
  __shared__ float tile[32][33];
  int tx = threadIdx.x & 31, ty = threadIdx.x >> 5;
  for (int i = ty; i < 32; i += 8) {
    int k = k0 + i, c = c0 + tx;
    float v = (k < DD) ? Ws[(size_t)k * DD + c] : Wn[(size_t)(k - DD) * DD + c];
    tile[i][tx] = v;
  }
  __syncthreads();
  for (int i = ty; i < 32; i += 8) {
    int c = c0 + i, k = k0 + tx;
    Wt[(size_t)c * KCAT + k] = (__bf16)tile[tx][i];
  }
}

// ---------------- mean aggregation: XCD-pinned slices, 4 edges/load (R4, proven) ---
__global__ __launch_bounds__(256) void k_agg(__bf16* __restrict__ buf,
                                             const int* __restrict__ off,
                                             const int* __restrict__ eidx) {
  const int s    = blockIdx.x & 7;
  const int q    = blockIdx.x >> 3;
  const int lane = threadIdx.x & 63;
  const int w    = threadIdx.x >> 6;
  const int g    = lane >> 4;
  const int l    = lane & 15;
  const int wid  = q * 4 + w;
  const size_t colb = (size_t)s * 128 + l * 8;

  for (int n = wid; n < N_NODES; n += AGG_WPS) {
    const int s0 = off[n], e0 = off[n + 1];
    float acc[8];
#pragma unroll
    for (int j = 0; j < 8; ++j) acc[j] = 0.f;
    int i = s0;
    for (; i + 8 <= e0; i += 8) {
      int eA = eidx[i + g];
      int eB = eidx[i + 4 + g];
      bf16x8 vA = *(const bf16x8*)(buf + (size_t)eA * KCAT + colb);
      bf16x8 vB = *(const bf16x8*)(buf + (size_t)eB * KCAT + colb);
#pragma unroll
      for (int j = 0; j < 8; ++j) acc[j] += (float)vA[j] + (float)vB[j];
    }
    if (i + 4 <= e0) {
      int eA = eidx[i + g];
      bf16x8 vA = *(const bf16x8*)(buf + (size_t)eA * KCAT + colb);
#pragma unroll
      for (int j = 0; j < 8; ++j) acc[j] += (float)vA[j];
      i += 4;
    }
    int rem = e0 - i;
    if (g < rem) {
      int eA = eidx[i + g];
      bf16x8 vA = *(const bf16x8*)(buf + (size_t)eA * KCAT + colb);
#pragma unroll
      for (int j = 0; j < 8; ++j) acc[j] += (float)vA[j];
    }
#pragma unroll
    for (int j = 0; j < 8; ++j) {
      acc[j] += __shfl_xor(acc[j], 16);
      acc[j] += __shfl_xor(acc[j], 32);
    }
    if (g == 0) {
      float inv = 1.0f / fmaxf((float)(e0 - s0), 1.0f);
      bf16x8 o;
#pragma unroll
      for (int j = 0; j < 8; ++j) o[j] = (__bf16)(acc[j] * inv);
      *(bf16x8*)(buf + (size_t)n * KCAT + DD + colb) = o;
    }
  }
}

// ---------------- GEMM: 256x256 tile, 8 waves (2Mx4N), BK=64, 4-phase schedule ----
// Per wave: 128x64 output = 8 m-frags x 4 n-frags (B reused 8x, A 4x -> MFMA-bound).
// LDS 128KB: 2 dbuf x (A[256][64] 32KB | B[256][64] 32KB). Swizzle (T2): physical
// 16B-chunk pc = cc ^ (row&7), applied on BOTH staging source and ds_read (rule 21,
// proven in R2). Per K-tile, 4 phases: {4-8 ds_read | stage kt+1 (A rounds @p0,
// B rounds @p1 -> >=2-phase flight) | raw barrier | lgkmcnt(0)+sched_barrier |
// setprio(1) 16 MFMA setprio(0) | barrier}. vmcnt(0) once per tile at p3 (T4-lite).
// Grid 160 = 8 XCD x 20 contiguous logical tiles (bijective), 1 block/CU.
template <int MODE>
__global__ __launch_bounds__(512, 2) void k_gemm(const __bf16* __restrict__ A,
                                                 const __bf16* __restrict__ Bt,
                                                 const float* __restrict__ bias,
                                                 float* __restrict__ Cf,
                                                 __bf16* __restrict__ Cb,
                                                 int Mreal) {
  __shared__ char smem[131072];
  const int tid  = threadIdx.x;
  const int lane = tid & 63;
  const int w    = tid >> 6;           // 0..7
  const int wr   = w >> 2;             // 0..1  (M)
  const int wc   = w & 3;              // 0..3  (N)
  const int b    = blockIdx.x;
  const int l    = (b & 7) * 20 + (b >> 3);   // XCD-chunked, bijective (160=8*20)
  const int m0   = (l >> 2) * 256;
  const int n0   = (l & 3) * 256;

  f32x4 acc[8][4];
#pragma unroll
  for (int m = 0; m < 8; ++m)
#pragma unroll
    for (int n = 0; n < 4; ++n) acc[m][n] = f32x4{0.f, 0.f, 0.f, 0.f};

  // stage one 8KB round: rows 64i..64i+63 of a [256][64] tile into linear LDS;
  // source chunk cc = pc ^ (row&7)  (inverse of the ds_read swizzle)
  auto stage_round = [&](char* dstbase, const __bf16* S, int gbase, int kt, int i) {
    int G   = i * 512 + tid;
    int row = G >> 3;
    int cc  = (G & 7) ^ (row & 7);
    gload_lds16(S + (size_t)(gbase + row) * KCAT + kt * 64 + cc * 8,
                dstbase + i * 8192 + w * 1024 + lane * 16);
  };

  char* A0 = smem;               // buf0: A @0, B @32768 ; buf1: A @65536, B @98304
  // prologue: stage tile 0 into buf0, drain, certify
  {
#pragma unroll
    for (int i = 0; i < 4; ++i) stage_round(A0, A, m0, 0, i);
#pragma unroll
    for (int i = 0; i < 4; ++i) stage_round(A0 + 32768, Bt, n0, 0, i);
  }
  asm volatile("s_waitcnt vmcnt(0)" ::: "memory");
  __builtin_amdgcn_sched_barrier(0);
  __builtin_amdgcn_s_barrier();
  __builtin_amdgcn_sched_barrier(0);

  for (int kt = 0; kt < NKT; ++kt) {
    char* Abuf  = smem + (kt & 1) * 65536;
    char* Bbuf  = Abuf + 32768;
    char* AbufN = smem + ((kt & 1) ^ 1) * 65536;
    char* BbufN = AbufN + 32768;
    bf16x8 bfr[4][2];
#pragma unroll
    for (int p = 0; p < 4; ++p) {
      // ---- ds_read this phase's fragments (swizzled; 2-way banks = free) ----
      bf16x8 af[2][2];
#pragma unroll
      for (int i = 0; i < 2; ++i)
#pragma unroll
        for (int kk = 0; kk < 2; ++kk) {
          int row = wr * 128 + (2 * p + i) * 16 + (lane & 15);
          int c   = kk * 4 + (lane >> 4);
          af[i][kk] = *(const bf16x8*)(Abuf + row * 128 + ((c ^ (row & 7)) << 4));
        }
      if (p == 0) {
#pragma unroll
        for (int nf = 0; nf < 4; ++nf)
#pragma unroll
          for (int kk = 0; kk < 2; ++kk) {
            int row = wc * 64 + nf * 16 + (lane & 15);
            int c   = kk * 4 + (lane >> 4);
            bfr[nf][kk] = *(const bf16x8*)(Bbuf + row * 128 + ((c ^ (row & 7)) << 4));
          }
      }
      // ---- front-loaded staging of tile kt+1 into the other buffer ----
      if (kt + 1 < NKT) {
        if (p == 0) {
#pragma unroll
          for (int i = 0; i < 4; ++i) stage_round(AbufN, A, m0, kt + 1, i);
        } else if (p == 1) {
#pragma unroll
          for (int i = 0; i < 4; ++i) stage_round(BbufN, Bt, n0, kt + 1, i);
        }
      }
      if (p == 3) {
        // once per tile: certify kt+1's loads (issued >=2 phases ago)
        asm volatile("s_waitcnt vmcnt(0)" ::: "memory");
      }
      __builtin_amdgcn_sched_barrier(0);
      __builtin_amdgcn_s_barrier();
      asm volatile("s_waitcnt lgkmcnt(0)" ::: "memory");
      __builtin_amdgcn_sched_barrier(0);
      __builtin_amdgcn_s_setprio(1);
#pragma unroll
      for (int i = 0; i < 2; ++i)
#pragma unroll
        for (int nf = 0; nf < 4; ++nf)
#pragma unroll
          for (int kk = 0; kk < 2; ++kk)
            acc[2 * p + i][nf] = __builtin_amdgcn_mfma_f32_16x16x32_bf16(
                af[i][kk], bfr[nf][kk], acc[2 * p + i][nf], 0, 0, 0);
      __builtin_amdgcn_s_setprio(0);
      __builtin_amdgcn_sched_barrier(0);
      __builtin_amdgcn_s_barrier();
      __builtin_amdgcn_sched_barrier(0);
    }
  }

  // epilogue: C/D layout col=lane&15, row=(lane>>4)*4+j (m89-verified, proven R2)
  const int rb = m0 + wr * 128;
  const int cb = n0 + wc * 64;
#pragma unroll
  for (int m = 0; m < 8; ++m) {
#pragma unroll
    for (int n = 0; n < 4; ++n) {
      int cc = cb + n * 16 + (lane & 15);
      float bv = bias[cc];
#pragma unroll
      for (int j = 0; j < 4; ++j) {
        int r = rb + m * 16 + (lane >> 4) * 4 + j;
        if (r < Mreal) {
          float v = acc[m][n][j] + bv;
          if constexpr (MODE == 1) {
            v = fmaxf(v, 0.f);
            Cb[(size_t)r * KCAT + cc] = (__bf16)v;
          } else {
            Cf[(size_t)r * DD + cc] = v;
          }
        }
      }
    }
  }
}

// ---------------- launcher ----------------
extern "C" void kernel_launch(void* const* d_in, const int* in_sizes, int n_in,
                              void* d_out, int out_size, void* d_ws, size_t ws_size,
                              hipStream_t stream) {
  const int*   node = (const int*)d_in[0];
  const int*   srcv = (const int*)d_in[1];
  const int*   dstv = (const int*)d_in[2];
  const float* emb  = (const float*)d_in[3];
  const float* W1s  = (const float*)d_in[4];
  const float* W1n  = (const float*)d_in[5];
  const float* b1   = (const float*)d_in[6];
  const float* W2s  = (const float*)d_in[7];
  const float* W2n  = (const float*)d_in[8];
  const float* b2   = (const float*)d_in[9];
  float* out = (float*)d_out;

  char* ws = (char*)d_ws;
  __bf16* xcat = (__bf16*)ws; ws += (size_t)MPAD * KCAT * 2;   // [x | hneigh1]
  __bf16* hcat = (__bf16*)ws; ws += (size_t)MPAD * KCAT * 2;   // [h1 | hneigh2]
  __bf16* Wt1  = (__bf16*)ws; ws += (size_t)DD * KCAT * 2;
  __bf16* Wt2  = (__bf16*)ws; ws += (size_t)DD * KCAT * 2;
  int* deg    = (int*)ws; ws += 40960;
  int* cursor = (int*)ws; ws += 40960;
  int* off    = (int*)ws; ws += 40960;
  int* eidx   = (int*)ws; ws += (size_t)N_EDGES * 4;

  hipMemsetAsync(deg, 0, 2 * 40960, stream);   // deg + cursor contiguous

  k_prep1<<<625 + N_NODES, 256, 0, stream>>>(dstv, deg, node, emb, xcat);
  k_scan<<<1, 1024, 0, stream>>>(deg, off);
  k_prep2<<<625 + 4096, 256, 0, stream>>>(srcv, dstv, off, cursor, eidx,
                                          W1s, W1n, W2s, W2n, Wt1, Wt2);

  // layer 1
  k_agg<<<AGG_BLOCKS, 256, 0, stream>>>(xcat, off, eidx);
  k_gemm<1><<<GBLK, 512, 0, stream>>>(xcat, Wt1, b1, nullptr, hcat, N_NODES);

  // layer 2
  k_agg<<<AGG_BLOCKS, 256, 0, stream>>>(hcat, off, eidx);
  k_gemm<0><<<GBLK, 512, 0, stream>>>(hcat, Wt2, b2, out, nullptr, N_NODES);
}